// Round 2
// baseline (434.262 us; speedup 1.0000x reference)
//
#include <hip/hip_runtime.h>

// FlowNetC correlation: B=8, C=128, H=128, W=256, PAD=4, MD=4, K=1, S1=S2=1
// out[b, dyi*9+dxi, h, w] = (1/128) * sum_c in1[b,c,h,w] * in2[b,c,h+dyi-4,w+dxi-4]
// (in2 zero outside bounds)
//
// R4 (resubmit; infra failed twice, never measured): shuffle-for-edge-loads +
// occupancy pin.
// Wave = one (b, h-pair, dy): 64 lanes x 8 px = 512 px = 2 rows of W=256.
// Per channel: in1 = 2 float4 loads, in2 = 2 float4 loads (w0..w0+7 only).
// The +/-4 window edges (w0-4..w0-1, w0+8..w0+11) come from neighbor lanes
// via __shfl (ds_bpermute) instead of 2 extra overlapping float4 loads:
// VMEM insts/channel 6->4, issued load bytes -33%, 2 pointer chains removed.
// Cross-lane garbage (sub-row boundary lane 31<->32, wave edges) feeds only
// acc entries the epilogue already kills.
// __launch_bounds__(256,4): pin <=128 VGPR -> 4 waves/SIMD for latency hiding.

#define NB 8
#define NC 128
#define NH 128
#define NW 256
#define ND 9
#define CH 32768                 // NH*NW floats = channel stride
#define SCALE (1.0f / 128.0f)

__global__ __launch_bounds__(256, 4) void corr_kernel(
    const float* __restrict__ in1, const float* __restrict__ in2,
    float* __restrict__ out)
{
    // 1152 blocks x 4 waves = 4608 waves = 8 b x 64 hp x 9 dy.
    // XCD swizzle: consecutive blockIdx round-robin XCDs, so give XCD x the
    // contiguous id range [x*576, (x+1)*576) -> each XCD owns exactly one b.
    const int bid = blockIdx.x;
    const int id  = ((bid & 7) * 144 + (bid >> 3)) * 4 + (threadIdx.x >> 6);
    const int g   = threadIdx.x & 63;

    const int dyi  = id % ND;
    const int rest = id / ND;        // 0..511
    const int hp   = rest & 63;
    const int b    = rest >> 6;

    const int r  = g >> 5;           // sub-row 0/1
    const int L  = g & 31;           // lane within row
    const int w0 = L << 3;           // 8 px per lane: w0..w0+7
    const int h  = (hp << 1) + r;    // output row (per-lane)
    const int hh = h + dyi - 4;      // in2 source row (per-lane)
    const bool valid = ((unsigned)hh < (unsigned)NH);
    const int hhc = valid ? hh : 0;  // clamped for safe addressing

    const float* aq = in1 + (size_t)(b * NC * NH + h)   * NW + w0;
    const float* bq = in2 + (size_t)(b * NC * NH + hhc) * NW + w0;

    float acc[8][ND];
#pragma unroll
    for (int p = 0; p < 8; ++p)
#pragma unroll
        for (int d = 0; d < ND; ++d) acc[p][d] = 0.f;

    // prefetch channel 0
    float4 A0 = *(const float4*)(aq);
    float4 A1 = *(const float4*)(aq + 4);
    float4 B1 = *(const float4*)(bq);
    float4 B2 = *(const float4*)(bq + 4);

#pragma unroll 2
    for (int c = 0; c < NC - 1; ++c) {
        // window edges for the CURRENT channel from neighbor lanes:
        // bw[0..3]   = lane g-1's B2 = in2[w0-4 .. w0-1]
        // bw[12..15] = lane g+1's B1 = in2[w0+8 .. w0+11]
        const float e0x = __shfl(B2.x, g - 1);
        const float e0y = __shfl(B2.y, g - 1);
        const float e0z = __shfl(B2.z, g - 1);
        const float e0w = __shfl(B2.w, g - 1);
        const float e3x = __shfl(B1.x, g + 1);
        const float e3y = __shfl(B1.y, g + 1);
        const float e3z = __shfl(B1.z, g + 1);
        const float e3w = __shfl(B1.w, g + 1);

        const float a_[8]  = {A0.x, A0.y, A0.z, A0.w, A1.x, A1.y, A1.z, A1.w};
        const float bw[16] = {e0x,  e0y,  e0z,  e0w,
                              B1.x, B1.y, B1.z, B1.w,
                              B2.x, B2.y, B2.z, B2.w,
                              e3x,  e3y,  e3z,  e3w};

        // prefetch next channel while computing this one
        aq += CH; bq += CH;
        A0 = *(const float4*)(aq);
        A1 = *(const float4*)(aq + 4);
        B1 = *(const float4*)(bq);
        B2 = *(const float4*)(bq + 4);

#pragma unroll
        for (int p = 0; p < 8; ++p)
#pragma unroll
            for (int d = 0; d < ND; ++d)
                acc[p][d] += a_[p] * bw[p + d];
    }
    {   // tail channel (last prefetch)
        const float e0x = __shfl(B2.x, g - 1);
        const float e0y = __shfl(B2.y, g - 1);
        const float e0z = __shfl(B2.z, g - 1);
        const float e0w = __shfl(B2.w, g - 1);
        const float e3x = __shfl(B1.x, g + 1);
        const float e3y = __shfl(B1.y, g + 1);
        const float e3z = __shfl(B1.z, g + 1);
        const float e3w = __shfl(B1.w, g + 1);

        const float a_[8]  = {A0.x, A0.y, A0.z, A0.w, A1.x, A1.y, A1.z, A1.w};
        const float bw[16] = {e0x,  e0y,  e0z,  e0w,
                              B1.x, B1.y, B1.z, B1.w,
                              B2.x, B2.y, B2.z, B2.w,
                              e3x,  e3y,  e3z,  e3w};
#pragma unroll
        for (int p = 0; p < 8; ++p)
#pragma unroll
            for (int d = 0; d < ND; ++d)
                acc[p][d] += a_[p] * bw[p + d];
    }

    // epilogue: zero the entries whose in2 sample is out of bounds
    float* outp = out + ((size_t)(b * (ND * ND) + dyi * ND) * NH + h) * NW + w0;
#pragma unroll
    for (int d = 0; d < ND; ++d) {
        float v[8];
#pragma unroll
        for (int p = 0; p < 8; ++p) {
            const bool kill = (!valid) ||
                              (L == 0  && (p + d) < 4) ||    // w-sample < 0
                              (L == 31 && (p + d) > 11);     // w-sample > 255
            v[p] = kill ? 0.0f : acc[p][d] * SCALE;
        }
        float4 lo = {v[0], v[1], v[2], v[3]};
        float4 hi = {v[4], v[5], v[6], v[7]};
        *(float4*)(outp + (size_t)d * CH)     = lo;
        *(float4*)(outp + (size_t)d * CH + 4) = hi;
    }
}

extern "C" void kernel_launch(void* const* d_in, const int* in_sizes, int n_in,
                              void* d_out, int out_size, void* d_ws, size_t ws_size,
                              hipStream_t stream) {
    const float* in1 = (const float*)d_in[0];
    const float* in2 = (const float*)d_in[1];
    float* out = (float*)d_out;
    corr_kernel<<<dim3(1152), dim3(256), 0, stream>>>(in1, in2, out);
}